// Round 1
// baseline (1249.727 us; speedup 1.0000x reference)
//
#include <hip/hip_runtime.h>
#include <hip/hip_bf16.h>

#define HID 128
#define DIN 192      // N_FEAT + NUM_SEM
#define NCH 65536
#define NE  1048576

// MFMA fragment types for gfx950 mfma_f32_16x16x32_bf16 (clang builtin sig V4fV8yV8yV4f)
typedef __bf16 bfrag __attribute__((ext_vector_type(8)));
typedef float  ffrag __attribute__((ext_vector_type(4)));

static __device__ __forceinline__ __bf16 f2bf(float x) { return (__bf16)x; }

// ---------------------------------------------------------------------------
// Child encoder: xNew[n][h] = relu(cf[n]@Wc + bc) * exists[n]   (fp32 out)
// MFMA: M=65536 rows (4096 tiles of 16), K=192 (6 ktiles), N=128 (8 utiles)
// ---------------------------------------------------------------------------
__global__ __launch_bounds__(256) void k_child(
    const float* __restrict__ cf, const float* __restrict__ exists,
    const float* __restrict__ Wc, const float* __restrict__ bc,
    float* __restrict__ xNew)
{
    __shared__ __bf16 Wl[6 * 8 * 64 * 8];   // 48 KB, B-fragment-swizzled
    __shared__ float  bl[HID];
    const int t = threadIdx.x;

    for (int idx = t; idx < DIN * HID; idx += 256) {
        int k = idx >> 7, h = idx & 127;
        int kt = k >> 5, kk = k & 31;
        int lane = ((kk >> 3) << 4) | (h & 15);     // quad = kk>>3, m = h&15
        Wl[((((kt * 8) + (h >> 4)) * 64 + lane) << 3) | (kk & 7)] = f2bf(Wc[idx]);
    }
    for (int idx = t; idx < HID; idx += 256) bl[idx] = bc[idx];
    __syncthreads();

    const int wave = t >> 6, lane = t & 63;
    const int m = lane & 15, quad = lane >> 4;

    const int tile = blockIdx.x * 4 + wave;   // grid 1024 -> 4096 tiles
    const int r0 = tile << 4;
    const int row = r0 + m;

    ffrag acc[8];
    #pragma unroll
    for (int u = 0; u < 8; ++u)
        #pragma unroll
        for (int r = 0; r < 4; ++r) acc[u][r] = 0.f;

    const float* arow = cf + (size_t)row * DIN + quad * 8;
    #pragma unroll
    for (int kt = 0; kt < 6; ++kt) {
        float4 f0 = *(const float4*)(arow + kt * 32);
        float4 f1 = *(const float4*)(arow + kt * 32 + 4);
        bfrag a;
        a[0]=f2bf(f0.x); a[1]=f2bf(f0.y); a[2]=f2bf(f0.z); a[3]=f2bf(f0.w);
        a[4]=f2bf(f1.x); a[5]=f2bf(f1.y); a[6]=f2bf(f1.z); a[7]=f2bf(f1.w);
        #pragma unroll
        for (int u = 0; u < 8; ++u) {
            bfrag b = *(const bfrag*)(&Wl[(((kt * 8 + u) * 64 + lane) << 3)]);
            acc[u] = __builtin_amdgcn_mfma_f32_16x16x32_bf16(a, b, acc[u], 0, 0, 0);
        }
    }

    // epilogue: C/D layout row=quad*4+r, col=u*16+m
    #pragma unroll
    for (int r = 0; r < 4; ++r) {
        int er = r0 + quad * 4 + r;
        float exv = exists[er];
        #pragma unroll
        for (int u = 0; u < 8; ++u) {
            int col = u * 16 + m;
            float v = fmaxf(acc[u][r] + bl[col], 0.f) * exv;
            xNew[(size_t)er * HID + col] = v;
        }
    }
}

// ---------------------------------------------------------------------------
// Finalize a stage: column-max of xNew into pmax[stage], optional bf16 copy
// to xA (for next gather), optional zeroing of xNew (for next segment_sum).
// flags: bit0 = write xA, bit1 = zero xNew
// ---------------------------------------------------------------------------
__global__ __launch_bounds__(256) void k_fin(
    float* __restrict__ xNew, __bf16* __restrict__ xA,
    unsigned int* __restrict__ pmax, int stage, int flags)
{
    const int t = threadIdx.x;
    const size_t total  = (size_t)NCH * HID;
    const size_t stride = (size_t)gridDim.x * 256;   // multiple of 128 -> col fixed
    float mx = 0.f;                                   // all values >= 0 (post-relu)
    for (size_t i = (size_t)blockIdx.x * 256 + t; i < total; i += stride) {
        float v = xNew[i];
        mx = fmaxf(mx, v);
        if (flags & 1) xA[i] = f2bf(v);
        if (flags & 2) xNew[i] = 0.f;
    }
    __shared__ float red[256];
    red[t] = mx;
    __syncthreads();
    if (t < 128) {
        float v = fmaxf(red[t], red[t + 128]);
        atomicMax(&pmax[stage * HID + t], __float_as_uint(v));  // v>=0: uint order ok
    }
}

// ---------------------------------------------------------------------------
// Edge message pass: nef = relu([x[src], x[dst], ef] @ We + be);
// xNew[src] += nef  (atomicAdd).  K = 256 (gathered x) + 8 (ef, as 9th ktile).
// ---------------------------------------------------------------------------
__global__ __launch_bounds__(256) void k_edge(
    const __bf16* __restrict__ xA,
    const int*    __restrict__ eidx,
    const float*  __restrict__ ef,
    const float*  __restrict__ We,    // 264 x 128 slice for this iteration
    const float*  __restrict__ be,    // 128
    float* __restrict__ xNew)
{
    __shared__ __bf16 Wl[9 * 8 * 64 * 8];  // 72 KB
    __shared__ float  bl[HID];
    const int t = threadIdx.x;

    // zero ktile 8 (pad region beyond the 8 ef rows)
    for (int idx = t; idx < 8 * 64 * 8; idx += 256) Wl[8 * 8 * 64 * 8 + idx] = (__bf16)0.f;
    __syncthreads();
    // main W rows k<256
    for (int idx = t; idx < 256 * HID; idx += 256) {
        int k = idx >> 7, h = idx & 127;
        int kt = k >> 5, kk = k & 31;
        int lane = ((kk >> 3) << 4) | (h & 15);
        Wl[((((kt * 8) + (h >> 4)) * 64 + lane) << 3) | (kk & 7)] = f2bf(We[idx]);
    }
    // ef rows k=256..263 -> ktile 8, quad 0, j=k2
    for (int idx = t; idx < 8 * HID; idx += 256) {
        int k2 = idx >> 7, h = idx & 127;
        Wl[((((8 * 8) + (h >> 4)) * 64 + (h & 15)) << 3) | k2] = f2bf(We[(256 + k2) * HID + h]);
    }
    for (int idx = t; idx < HID; idx += 256) bl[idx] = be[idx];
    __syncthreads();

    const int wave = t >> 6, lane = t & 63;
    const int m = lane & 15, quad = lane >> 4;

    for (int c = 0; c < 8; ++c) {                      // 512 edges per block
        const int e0 = blockIdx.x * 512 + c * 64 + wave * 16;
        const int e  = e0 + m;                         // A-row owned by this lane
        const int src = eidx[2 * e], dst = eidx[2 * e + 1];
        const __bf16* rs = xA + (size_t)src * HID;
        const __bf16* rd = xA + (size_t)dst * HID;

        bfrag a[9];
        #pragma unroll
        for (int kt = 0; kt < 4; ++kt) a[kt] = *(const bfrag*)(rs + kt * 32 + quad * 8);
        #pragma unroll
        for (int kt = 4; kt < 8; ++kt) a[kt] = *(const bfrag*)(rd + (kt - 4) * 32 + quad * 8);
        {
            bfrag z;
            #pragma unroll
            for (int j = 0; j < 8; ++j) z[j] = (__bf16)0.f;
            if (quad == 0) {
                const float4* p = (const float4*)(ef + (size_t)e * 8);
                float4 f0 = p[0], f1 = p[1];
                z[0]=f2bf(f0.x); z[1]=f2bf(f0.y); z[2]=f2bf(f0.z); z[3]=f2bf(f0.w);
                z[4]=f2bf(f1.x); z[5]=f2bf(f1.y); z[6]=f2bf(f1.z); z[7]=f2bf(f1.w);
            }
            a[8] = z;
        }

        ffrag acc[8];
        #pragma unroll
        for (int u = 0; u < 8; ++u)
            #pragma unroll
            for (int r = 0; r < 4; ++r) acc[u][r] = 0.f;

        #pragma unroll
        for (int kt = 0; kt < 9; ++kt) {
            #pragma unroll
            for (int u = 0; u < 8; ++u) {
                bfrag b = *(const bfrag*)(&Wl[(((kt * 8 + u) * 64 + lane) << 3)]);
                acc[u] = __builtin_amdgcn_mfma_f32_16x16x32_bf16(a[kt], b, acc[u], 0, 0, 0);
            }
        }

        // epilogue: bias + relu + segment_sum scatter (row = quad*4+r, col = u*16+m)
        #pragma unroll
        for (int r = 0; r < 4; ++r) {
            int er = e0 + quad * 4 + r;
            int sr = eidx[2 * er];
            float* outrow = xNew + (size_t)sr * HID;
            #pragma unroll
            for (int u = 0; u < 8; ++u) {
                int col = u * 16 + m;
                float v = fmaxf(acc[u][r] + bl[col], 0.f);
                atomicAdd(outrow + col, v);
            }
        }
    }
}

// ---------------------------------------------------------------------------
// Parent head: out = relu(pmax(384) @ Wp + bp), single block of 128 threads
// ---------------------------------------------------------------------------
__global__ __launch_bounds__(128) void k_parent(
    const unsigned int* __restrict__ pmaxU,
    const float* __restrict__ Wp, const float* __restrict__ bp,
    float* __restrict__ out)
{
    __shared__ float pl[384];
    const int t = threadIdx.x;
    for (int i = t; i < 384; i += 128) pl[i] = __uint_as_float(pmaxU[i]);
    __syncthreads();
    float acc = bp[t];
    for (int j = 0; j < 384; ++j) acc += pl[j] * Wp[j * HID + t];
    out[t] = fmaxf(acc, 0.f);
}

extern "C" void kernel_launch(void* const* d_in, const int* in_sizes, int n_in,
                              void* d_out, int out_size, void* d_ws, size_t ws_size,
                              hipStream_t stream)
{
    const float* cf   = (const float*)d_in[0];
    const float* ex   = (const float*)d_in[1];
    const float* ef   = (const float*)d_in[2];
    const int*   eidx = (const int*)d_in[3];
    const float* Wc   = (const float*)d_in[4];
    const float* bc   = (const float*)d_in[5];
    const float* We   = (const float*)d_in[6];
    const float* be   = (const float*)d_in[7];
    const float* Wp   = (const float*)d_in[8];
    const float* bp   = (const float*)d_in[9];
    float* out = (float*)d_out;

    char* ws = (char*)d_ws;
    float*        xNew = (float*)ws;                                   // 32 MB fp32 accum
    __bf16*       xA   = (__bf16*)(ws + (size_t)NCH * HID * 4);        // 16 MB bf16 x
    unsigned int* pmax = (unsigned int*)(ws + (size_t)NCH * HID * 6);  // 384 * 4 B

    hipMemsetAsync(pmax, 0, 384 * sizeof(unsigned int), stream);

    k_child <<<1024, 256, 0, stream>>>(cf, ex, Wc, bc, xNew);
    k_fin   <<<512,  256, 0, stream>>>(xNew, xA, pmax, 0, 3);
    k_edge  <<<2048, 256, 0, stream>>>(xA, eidx, ef, We,             be,       xNew);
    k_fin   <<<512,  256, 0, stream>>>(xNew, xA, pmax, 1, 3);
    k_edge  <<<2048, 256, 0, stream>>>(xA, eidx, ef, We + 264 * HID, be + HID, xNew);
    k_fin   <<<512,  256, 0, stream>>>(xNew, xA, pmax, 2, 0);
    k_parent<<<1,    128, 0, stream>>>(pmax, Wp, bp, out);
}

// Round 2
// 1237.715 us; speedup vs baseline: 1.0097x; 1.0097x over previous
//
#include <hip/hip_runtime.h>
#include <hip/hip_bf16.h>

#define HID 128
#define DIN 192      // N_FEAT + NUM_SEM
#define NCH 65536
#define NE  1048576

// MFMA fragment types for gfx950 mfma_f32_16x16x32_bf16
typedef __bf16 bfrag __attribute__((ext_vector_type(8)));
typedef float  ffrag __attribute__((ext_vector_type(4)));

static __device__ __forceinline__ __bf16 f2bf(float x) { return (__bf16)x; }

// ---------------------------------------------------------------------------
// Child encoder fused: xA[n][h] = bf16(relu(cf[n]@Wc + bc) * exists[n]),
// plus column-max into pmax[0..127].
// ---------------------------------------------------------------------------
__global__ __launch_bounds__(256) void k_child(
    const float* __restrict__ cf, const float* __restrict__ exists,
    const float* __restrict__ Wc, const float* __restrict__ bc,
    __bf16* __restrict__ xA, unsigned int* __restrict__ pmax)
{
    __shared__ __bf16 Wl[6 * 8 * 64 * 8];   // 48 KB, B-fragment-swizzled
    __shared__ float  bl[HID];
    __shared__ unsigned int cm[HID];
    const int t = threadIdx.x;

    for (int idx = t; idx < DIN * HID; idx += 256) {
        int k = idx >> 7, h = idx & 127;
        int kt = k >> 5, kk = k & 31;
        int lane = ((kk >> 3) << 4) | (h & 15);     // quad = kk>>3, m = h&15
        Wl[((((kt * 8) + (h >> 4)) * 64 + lane) << 3) | (kk & 7)] = f2bf(Wc[idx]);
    }
    for (int idx = t; idx < HID; idx += 256) { bl[idx] = bc[idx]; cm[idx] = 0u; }
    __syncthreads();

    const int wave = t >> 6, lane = t & 63;
    const int m = lane & 15, quad = lane >> 4;

    const int tile = blockIdx.x * 4 + wave;   // grid 1024 -> 4096 tiles
    const int r0 = tile << 4;
    const int row = r0 + m;

    ffrag acc[8];
    #pragma unroll
    for (int u = 0; u < 8; ++u)
        #pragma unroll
        for (int r = 0; r < 4; ++r) acc[u][r] = 0.f;

    const float* arow = cf + (size_t)row * DIN + quad * 8;
    #pragma unroll
    for (int kt = 0; kt < 6; ++kt) {
        float4 f0 = *(const float4*)(arow + kt * 32);
        float4 f1 = *(const float4*)(arow + kt * 32 + 4);
        bfrag a;
        a[0]=f2bf(f0.x); a[1]=f2bf(f0.y); a[2]=f2bf(f0.z); a[3]=f2bf(f0.w);
        a[4]=f2bf(f1.x); a[5]=f2bf(f1.y); a[6]=f2bf(f1.z); a[7]=f2bf(f1.w);
        #pragma unroll
        for (int u = 0; u < 8; ++u) {
            bfrag b = *(const bfrag*)(&Wl[(((kt * 8 + u) * 64 + lane) << 3)]);
            acc[u] = __builtin_amdgcn_mfma_f32_16x16x32_bf16(a, b, acc[u], 0, 0, 0);
        }
    }

    // epilogue: C/D layout row=quad*4+r, col=u*16+m
    #pragma unroll
    for (int r = 0; r < 4; ++r) {
        int er = r0 + quad * 4 + r;
        float exv = exists[er];
        __bf16* orow = xA + (size_t)er * HID;
        #pragma unroll
        for (int u = 0; u < 8; ++u) {
            int col = u * 16 + m;
            float v = fmaxf(acc[u][r] + bl[col], 0.f) * exv;
            orow[col] = f2bf(v);
            atomicMax(&cm[col], __float_as_uint(v));   // v >= 0
        }
    }
    __syncthreads();
    if (t < HID) atomicMax(&pmax[t], cm[t]);
}

// ---------------------------------------------------------------------------
// CSR build: histogram, exclusive scan (single block), scatter of edge ids
// ---------------------------------------------------------------------------
__global__ __launch_bounds__(256) void k_hist(
    const int* __restrict__ eidx, int* __restrict__ deg)
{
    int e = blockIdx.x * 256 + threadIdx.x;
    atomicAdd(&deg[eidx[2 * e]], 1);
}

__global__ __launch_bounds__(1024) void k_scan(
    const int* __restrict__ deg, int* __restrict__ off, int* __restrict__ cursor)
{
    __shared__ int sc[1024];
    const int t = threadIdx.x;
    const int base = t * 64;
    int s = 0;
    for (int i = 0; i < 64; ++i) s += deg[base + i];
    sc[t] = s;
    __syncthreads();
    for (int o = 1; o < 1024; o <<= 1) {
        int v = (t >= o) ? sc[t - o] : 0;
        __syncthreads();
        sc[t] += v;
        __syncthreads();
    }
    int run = sc[t] - s;     // exclusive prefix for this thread's chunk
    for (int i = 0; i < 64; ++i) {
        int v = deg[base + i];
        off[base + i] = run;
        cursor[base + i] = run;
        run += v;
    }
    if (t == 1023) off[NCH] = run;
}

__global__ __launch_bounds__(256) void k_scatter(
    const int* __restrict__ eidx, int* __restrict__ cursor, int* __restrict__ perm)
{
    int e = blockIdx.x * 256 + threadIdx.x;
    int s = eidx[2 * e];
    int p = atomicAdd(&cursor[s], 1);
    perm[p] = e;
}

// ---------------------------------------------------------------------------
// Edge message pass: nef = relu([x[src], x[dst], ef] @ We + be)
// BUF=1: store bf16 nef rows to buf (no atomics).  BUF=0: atomicAdd into xNew.
// ---------------------------------------------------------------------------
template<int BUF>
__global__ __launch_bounds__(256) void k_edge(
    const __bf16* __restrict__ xA,
    const int*    __restrict__ eidx,
    const float*  __restrict__ ef,
    const float*  __restrict__ We,    // 264 x 128 slice for this iteration
    const float*  __restrict__ be,    // 128
    float* __restrict__ xNew,
    __bf16* __restrict__ buf)
{
    __shared__ __bf16 Wl[9 * 8 * 64 * 8];  // 72 KB
    __shared__ float  bl[HID];
    const int t = threadIdx.x;

    // zero ktile 8 (pad region beyond the 8 ef rows)
    for (int idx = t; idx < 8 * 64 * 8; idx += 256) Wl[8 * 8 * 64 * 8 + idx] = (__bf16)0.f;
    __syncthreads();
    // main W rows k<256
    for (int idx = t; idx < 256 * HID; idx += 256) {
        int k = idx >> 7, h = idx & 127;
        int kt = k >> 5, kk = k & 31;
        int lane = ((kk >> 3) << 4) | (h & 15);
        Wl[((((kt * 8) + (h >> 4)) * 64 + lane) << 3) | (kk & 7)] = f2bf(We[idx]);
    }
    // ef rows k=256..263 -> ktile 8, quad 0, j=k2
    for (int idx = t; idx < 8 * HID; idx += 256) {
        int k2 = idx >> 7, h = idx & 127;
        Wl[((((8 * 8) + (h >> 4)) * 64 + (h & 15)) << 3) | k2] = f2bf(We[(256 + k2) * HID + h]);
    }
    for (int idx = t; idx < HID; idx += 256) bl[idx] = be[idx];
    __syncthreads();

    const int wave = t >> 6, lane = t & 63;
    const int m = lane & 15, quad = lane >> 4;

    for (int c = 0; c < 8; ++c) {                      // 512 edges per block
        const int e0 = blockIdx.x * 512 + c * 64 + wave * 16;
        const int e  = e0 + m;                         // A-row owned by this lane
        const int src = eidx[2 * e], dst = eidx[2 * e + 1];
        const __bf16* rs = xA + (size_t)src * HID;
        const __bf16* rd = xA + (size_t)dst * HID;

        bfrag a[9];
        #pragma unroll
        for (int kt = 0; kt < 4; ++kt) a[kt] = *(const bfrag*)(rs + kt * 32 + quad * 8);
        #pragma unroll
        for (int kt = 4; kt < 8; ++kt) a[kt] = *(const bfrag*)(rd + (kt - 4) * 32 + quad * 8);
        {
            bfrag z;
            #pragma unroll
            for (int j = 0; j < 8; ++j) z[j] = (__bf16)0.f;
            if (quad == 0) {
                const float4* p = (const float4*)(ef + (size_t)e * 8);
                float4 f0 = p[0], f1 = p[1];
                z[0]=f2bf(f0.x); z[1]=f2bf(f0.y); z[2]=f2bf(f0.z); z[3]=f2bf(f0.w);
                z[4]=f2bf(f1.x); z[5]=f2bf(f1.y); z[6]=f2bf(f1.z); z[7]=f2bf(f1.w);
            }
            a[8] = z;
        }

        ffrag acc[8];
        #pragma unroll
        for (int u = 0; u < 8; ++u)
            #pragma unroll
            for (int r = 0; r < 4; ++r) acc[u][r] = 0.f;

        #pragma unroll
        for (int kt = 0; kt < 9; ++kt) {
            #pragma unroll
            for (int u = 0; u < 8; ++u) {
                bfrag b = *(const bfrag*)(&Wl[(((kt * 8 + u) * 64 + lane) << 3)]);
                acc[u] = __builtin_amdgcn_mfma_f32_16x16x32_bf16(a[kt], b, acc[u], 0, 0, 0);
            }
        }

        // epilogue (row = quad*4+r, col = u*16+m)
        #pragma unroll
        for (int r = 0; r < 4; ++r) {
            int er = e0 + quad * 4 + r;
            if (BUF) {
                __bf16* orow = buf + (size_t)er * HID;
                #pragma unroll
                for (int u = 0; u < 8; ++u) {
                    int col = u * 16 + m;
                    orow[col] = f2bf(fmaxf(acc[u][r] + bl[col], 0.f));
                }
            } else {
                int sr = eidx[2 * er];
                float* outrow = xNew + (size_t)sr * HID;
                #pragma unroll
                for (int u = 0; u < 8; ++u) {
                    int col = u * 16 + m;
                    atomicAdd(outrow + col, fmaxf(acc[u][r] + bl[col], 0.f));
                }
            }
        }
    }
}

// ---------------------------------------------------------------------------
// Gather: per node, sum its nef rows (CSR) in fp32; write xA bf16; fused
// column-max into pmax[stage]. One wave per node (strided).
// ---------------------------------------------------------------------------
__global__ __launch_bounds__(256) void k_gather(
    const __bf16* __restrict__ buf, const int* __restrict__ off,
    const int* __restrict__ perm, __bf16* __restrict__ xA,
    unsigned int* __restrict__ pmax, int stage)
{
    const int t = threadIdx.x, wave = t >> 6, lane = t & 63;
    const int gw = blockIdx.x * 4 + wave;
    const int nw = gridDim.x * 4;
    const unsigned short* bufu = (const unsigned short*)buf;
    float mx0 = 0.f, mx1 = 0.f;

    for (int n = gw; n < NCH; n += nw) {
        int j0 = off[n], j1 = off[n + 1];
        float a0 = 0.f, a1 = 0.f, b0 = 0.f, b1 = 0.f;
        int j = j0;
        for (; j + 1 < j1; j += 2) {
            int e0 = perm[j], e1 = perm[j + 1];
            unsigned v0 = *(const unsigned*)(bufu + (size_t)e0 * HID + lane * 2);
            unsigned v1 = *(const unsigned*)(bufu + (size_t)e1 * HID + lane * 2);
            a0 += __uint_as_float(v0 << 16); a1 += __uint_as_float(v0 & 0xffff0000u);
            b0 += __uint_as_float(v1 << 16); b1 += __uint_as_float(v1 & 0xffff0000u);
        }
        if (j < j1) {
            int e0 = perm[j];
            unsigned v0 = *(const unsigned*)(bufu + (size_t)e0 * HID + lane * 2);
            a0 += __uint_as_float(v0 << 16); a1 += __uint_as_float(v0 & 0xffff0000u);
        }
        a0 += b0; a1 += b1;
        __bf16 o0 = f2bf(a0), o1 = f2bf(a1);
        unsigned short s0 = *(unsigned short*)&o0, s1 = *(unsigned short*)&o1;
        *(unsigned*)((unsigned short*)xA + (size_t)n * HID + lane * 2) =
            (unsigned)s0 | ((unsigned)s1 << 16);
        mx0 = fmaxf(mx0, a0); mx1 = fmaxf(mx1, a1);
    }

    __shared__ unsigned int cm[HID];
    if (t < HID) cm[t] = 0u;
    __syncthreads();
    atomicMax(&cm[lane * 2],     __float_as_uint(mx0));
    atomicMax(&cm[lane * 2 + 1], __float_as_uint(mx1));
    __syncthreads();
    if (t < HID) atomicMax(&pmax[stage * HID + t], cm[t]);
}

// ---------------------------------------------------------------------------
// Fallback finalize (atomic path): column-max of xNew, bf16 copy, zeroing
// ---------------------------------------------------------------------------
__global__ __launch_bounds__(256) void k_fin(
    float* __restrict__ xNew, __bf16* __restrict__ xA,
    unsigned int* __restrict__ pmax, int stage, int flags)
{
    const int t = threadIdx.x;
    const size_t total  = (size_t)NCH * HID;
    const size_t stride = (size_t)gridDim.x * 256;
    float mx = 0.f;
    for (size_t i = (size_t)blockIdx.x * 256 + t; i < total; i += stride) {
        float v = xNew[i];
        mx = fmaxf(mx, v);
        if (flags & 1) xA[i] = f2bf(v);
        if (flags & 2) xNew[i] = 0.f;
    }
    __shared__ float red[256];
    red[t] = mx;
    __syncthreads();
    if (t < 128) {
        float v = fmaxf(red[t], red[t + 128]);
        atomicMax(&pmax[stage * HID + t], __float_as_uint(v));
    }
}

// ---------------------------------------------------------------------------
// Parent head: out = relu(pmax(384) @ Wp + bp)
// ---------------------------------------------------------------------------
__global__ __launch_bounds__(128) void k_parent(
    const unsigned int* __restrict__ pmaxU,
    const float* __restrict__ Wp, const float* __restrict__ bp,
    float* __restrict__ out)
{
    __shared__ float pl[384];
    const int t = threadIdx.x;
    for (int i = t; i < 384; i += 128) pl[i] = __uint_as_float(pmaxU[i]);
    __syncthreads();
    float acc = bp[t];
    for (int j = 0; j < 384; ++j) acc += pl[j] * Wp[j * HID + t];
    out[t] = fmaxf(acc, 0.f);
}

extern "C" void kernel_launch(void* const* d_in, const int* in_sizes, int n_in,
                              void* d_out, int out_size, void* d_ws, size_t ws_size,
                              hipStream_t stream)
{
    const float* cf   = (const float*)d_in[0];
    const float* ex   = (const float*)d_in[1];
    const float* ef   = (const float*)d_in[2];
    const int*   eidx = (const int*)d_in[3];
    const float* Wc   = (const float*)d_in[4];
    const float* bc   = (const float*)d_in[5];
    const float* We   = (const float*)d_in[6];
    const float* be   = (const float*)d_in[7];
    const float* Wp   = (const float*)d_in[8];
    const float* bp   = (const float*)d_in[9];
    float* out = (float*)d_out;

    char* ws = (char*)d_ws;

    // buffer-path workspace layout
    const size_t OFF_BUF  = 0;                                   // 256 MB bf16 nef
    const size_t OFF_XA   = OFF_BUF  + (size_t)NE * HID * 2;     // 16 MB bf16 x
    const size_t OFF_PERM = OFF_XA   + (size_t)NCH * HID * 2;    // 4 MB
    const size_t OFF_OFFS = OFF_PERM + (size_t)NE * 4;           // 65537 ints
    const size_t OFF_CUR  = OFF_OFFS + 262400;
    const size_t OFF_DEG  = OFF_CUR  + (size_t)NCH * 4;
    const size_t OFF_PMAX = OFF_DEG  + (size_t)NCH * 4;
    const size_t NEED     = OFF_PMAX + 2048;

    if (ws_size >= NEED) {
        __bf16*       buf    = (__bf16*)(ws + OFF_BUF);
        __bf16*       xA     = (__bf16*)(ws + OFF_XA);
        int*          perm   = (int*)   (ws + OFF_PERM);
        int*          offs   = (int*)   (ws + OFF_OFFS);
        int*          cursor = (int*)   (ws + OFF_CUR);
        int*          deg    = (int*)   (ws + OFF_DEG);
        unsigned int* pmax   = (unsigned int*)(ws + OFF_PMAX);

        hipMemsetAsync(pmax, 0, 384 * sizeof(unsigned int), stream);
        hipMemsetAsync(deg, 0, NCH * sizeof(int), stream);

        k_child  <<<1024, 256, 0, stream>>>(cf, ex, Wc, bc, xA, pmax);
        k_hist   <<<4096, 256, 0, stream>>>(eidx, deg);
        k_scan   <<<1,   1024, 0, stream>>>(deg, offs, cursor);
        k_scatter<<<4096, 256, 0, stream>>>(eidx, cursor, perm);

        k_edge<1><<<2048, 256, 0, stream>>>(xA, eidx, ef, We,             be,       nullptr, buf);
        k_gather <<<1024, 256, 0, stream>>>(buf, offs, perm, xA, pmax, 1);
        k_edge<1><<<2048, 256, 0, stream>>>(xA, eidx, ef, We + 264 * HID, be + HID, nullptr, buf);
        k_gather <<<1024, 256, 0, stream>>>(buf, offs, perm, xA, pmax, 2);
        k_parent <<<1,    128, 0, stream>>>(pmax, Wp, bp, out);
    } else {
        // fallback: R1 atomic path
        float*        xNew = (float*)ws;                                   // 32 MB
        __bf16*       xA   = (__bf16*)(ws + (size_t)NCH * HID * 4);        // 16 MB
        unsigned int* pmax = (unsigned int*)(ws + (size_t)NCH * HID * 6);

        hipMemsetAsync(pmax, 0, 384 * sizeof(unsigned int), stream);
        hipMemsetAsync(xNew, 0, (size_t)NCH * HID * 4, stream);

        k_child  <<<1024, 256, 0, stream>>>(cf, ex, Wc, bc, xA, pmax);
        k_edge<0><<<2048, 256, 0, stream>>>(xA, eidx, ef, We,             be,       xNew, nullptr);
        k_fin    <<<512,  256, 0, stream>>>(xNew, xA, pmax, 1, 3);
        k_edge<0><<<2048, 256, 0, stream>>>(xA, eidx, ef, We + 264 * HID, be + HID, xNew, nullptr);
        k_fin    <<<512,  256, 0, stream>>>(xNew, xA, pmax, 2, 0);
        k_parent <<<1,    128, 0, stream>>>(pmax, Wp, bp, out);
    }
}

// Round 3
// 892.632 us; speedup vs baseline: 1.4000x; 1.3866x over previous
//
#include <hip/hip_runtime.h>
#include <hip/hip_bf16.h>

#define HID 128
#define DIN 192      // N_FEAT + NUM_SEM
#define NCH 65536
#define NE  1048576

typedef __bf16 bfrag __attribute__((ext_vector_type(8)));
typedef float  ffrag __attribute__((ext_vector_type(4)));

static __device__ __forceinline__ __bf16 f2bf(float x) { return (__bf16)x; }
static __device__ __forceinline__ unsigned pk2(float a, float b) {
    __bf16 b0 = f2bf(a), b1 = f2bf(b);
    return (unsigned)*(unsigned short*)&b0 | ((unsigned)*(unsigned short*)&b1 << 16);
}

// ---------------------------------------------------------------------------
// Child encoder fused: xA[n][h] = bf16(relu(cf[n]@Wc + bc) * exists[n]),
// col-max into pmax[0..127] (register-max + shuffle, few LDS atomics).
// ---------------------------------------------------------------------------
__global__ __launch_bounds__(256) void k_child(
    const float* __restrict__ cf, const float* __restrict__ exists,
    const float* __restrict__ Wc, const float* __restrict__ bc,
    __bf16* __restrict__ xA, unsigned int* __restrict__ pmax)
{
    __shared__ __bf16 Wl[6 * 8 * 64 * 8];   // 48 KB, B-fragment-swizzled
    __shared__ float  bl[HID];
    __shared__ unsigned int cm[HID];
    const int t = threadIdx.x;

    for (int idx = t; idx < DIN * HID; idx += 256) {
        int k = idx >> 7, h = idx & 127;
        int kt = k >> 5, kk = k & 31;
        int lane = ((kk >> 3) << 4) | (h & 15);
        Wl[((((kt * 8) + (h >> 4)) * 64 + lane) << 3) | (kk & 7)] = f2bf(Wc[idx]);
    }
    for (int idx = t; idx < HID; idx += 256) { bl[idx] = bc[idx]; cm[idx] = 0u; }
    __syncthreads();

    const int wave = t >> 6, lane = t & 63;
    const int m = lane & 15, quad = lane >> 4;

    const int tile = blockIdx.x * 4 + wave;   // grid 1024 -> 4096 tiles
    const int r0 = tile << 4;
    const int row = r0 + m;

    ffrag acc[8];
    #pragma unroll
    for (int u = 0; u < 8; ++u)
        #pragma unroll
        for (int r = 0; r < 4; ++r) acc[u][r] = 0.f;

    const float* arow = cf + (size_t)row * DIN + quad * 8;
    #pragma unroll
    for (int kt = 0; kt < 6; ++kt) {
        float4 f0 = *(const float4*)(arow + kt * 32);
        float4 f1 = *(const float4*)(arow + kt * 32 + 4);
        bfrag a;
        a[0]=f2bf(f0.x); a[1]=f2bf(f0.y); a[2]=f2bf(f0.z); a[3]=f2bf(f0.w);
        a[4]=f2bf(f1.x); a[5]=f2bf(f1.y); a[6]=f2bf(f1.z); a[7]=f2bf(f1.w);
        #pragma unroll
        for (int u = 0; u < 8; ++u) {
            bfrag b = *(const bfrag*)(&Wl[(((kt * 8 + u) * 64 + lane) << 3)]);
            acc[u] = __builtin_amdgcn_mfma_f32_16x16x32_bf16(a, b, acc[u], 0, 0, 0);
        }
    }

    float mxu[8];
    #pragma unroll
    for (int u = 0; u < 8; ++u) mxu[u] = 0.f;

    #pragma unroll
    for (int r = 0; r < 4; ++r) {
        int er = r0 + quad * 4 + r;
        float exv = exists[er];
        __bf16* orow = xA + (size_t)er * HID;
        #pragma unroll
        for (int u = 0; u < 8; ++u) {
            int col = u * 16 + m;
            float v = fmaxf(acc[u][r] + bl[col], 0.f) * exv;
            orow[col] = f2bf(v);
            mxu[u] = fmaxf(mxu[u], v);
        }
    }
    #pragma unroll
    for (int u = 0; u < 8; ++u) {
        float v = mxu[u];
        v = fmaxf(v, __shfl_xor(v, 16));
        v = fmaxf(v, __shfl_xor(v, 32));
        if (quad == 0) atomicMax(&cm[u * 16 + m], __float_as_uint(v));
    }
    __syncthreads();
    if (t < HID) atomicMax(&pmax[t], cm[t]);
}

// ---------------------------------------------------------------------------
// CSR build: histogram, exclusive scan (single block), scatter of edge ids
// ---------------------------------------------------------------------------
__global__ __launch_bounds__(256) void k_hist(
    const int* __restrict__ eidx, int* __restrict__ deg)
{
    int e = blockIdx.x * 256 + threadIdx.x;
    atomicAdd(&deg[eidx[2 * e]], 1);
}

__global__ __launch_bounds__(1024) void k_scan(
    const int* __restrict__ deg, int* __restrict__ off, int* __restrict__ cursor)
{
    __shared__ int sc[1024];
    const int t = threadIdx.x;
    const int base = t * 64;
    int s = 0;
    for (int i = 0; i < 64; ++i) s += deg[base + i];
    sc[t] = s;
    __syncthreads();
    for (int o = 1; o < 1024; o <<= 1) {
        int v = (t >= o) ? sc[t - o] : 0;
        __syncthreads();
        sc[t] += v;
        __syncthreads();
    }
    int run = sc[t] - s;
    for (int i = 0; i < 64; ++i) {
        int v = deg[base + i];
        off[base + i] = run;
        cursor[base + i] = run;
        run += v;
    }
    if (t == 1023) off[NCH] = run;
}

__global__ __launch_bounds__(256) void k_scatter(
    const int* __restrict__ eidx, int* __restrict__ cursor, int* __restrict__ perm)
{
    int e = blockIdx.x * 256 + threadIdx.x;
    int s = eidx[2 * e];
    int p = atomicAdd(&cursor[s], 1);
    perm[p] = e;
}

// Pre-gather into sorted order: dsts[j], efs[j] (bf16).  dsts MAY alias perm
// (each thread reads perm[j] then writes dsts[j] — same index, no cross-use).
__global__ __launch_bounds__(256) void k_sortef(
    const int* __restrict__ eidx, const int* __restrict__ perm,
    const float* __restrict__ ef,
    int* __restrict__ dsts, __bf16* __restrict__ efs)
{
    int j = blockIdx.x * 256 + threadIdx.x;
    int e = perm[j];
    int d = eidx[2 * e + 1];
    const float4* p = (const float4*)(ef + (size_t)e * 8);
    float4 f0 = p[0], f1 = p[1];
    dsts[j] = d;
    unsigned* o = (unsigned*)(efs + (size_t)j * 8);
    o[0] = pk2(f0.x, f0.y); o[1] = pk2(f0.z, f0.w);
    o[2] = pk2(f1.x, f1.y); o[3] = pk2(f1.z, f1.w);
}

// ---------------------------------------------------------------------------
// S = x @ We[0:128]  (no bias/relu), stored TRANSPOSED bf16: St[col*NCH+node]
// so the epilogue packs 4 consecutive rows into one 8B store.
// ---------------------------------------------------------------------------
__global__ __launch_bounds__(256) void k_src(
    const __bf16* __restrict__ xCur, const float* __restrict__ We,
    __bf16* __restrict__ St)
{
    __shared__ __bf16 Wl[4 * 8 * 64 * 8];   // 32 KB
    const int t = threadIdx.x;
    for (int idx = t; idx < 128 * HID; idx += 256) {
        int k = idx >> 7, h = idx & 127;
        int kt = k >> 5, kk = k & 31;
        int lane = ((kk >> 3) << 4) | (h & 15);
        Wl[((((kt * 8) + (h >> 4)) * 64 + lane) << 3) | (kk & 7)] = f2bf(We[idx]);
    }
    __syncthreads();

    const int wave = t >> 6, lane = t & 63;
    const int m = lane & 15, quad = lane >> 4;
    const int tile = blockIdx.x * 4 + wave;   // grid 1024 -> 4096 tiles
    const int r0 = tile << 4;
    const int row = r0 + m;

    ffrag acc[8];
    #pragma unroll
    for (int u = 0; u < 8; ++u)
        #pragma unroll
        for (int r = 0; r < 4; ++r) acc[u][r] = 0.f;

    const __bf16* ar = xCur + (size_t)row * HID + quad * 8;
    #pragma unroll
    for (int kt = 0; kt < 4; ++kt) {
        bfrag a = *(const bfrag*)(ar + kt * 32);
        #pragma unroll
        for (int u = 0; u < 8; ++u) {
            bfrag b = *(const bfrag*)(&Wl[(((kt * 8 + u) * 64 + lane) << 3)]);
            acc[u] = __builtin_amdgcn_mfma_f32_16x16x32_bf16(a, b, acc[u], 0, 0, 0);
        }
    }
    #pragma unroll
    for (int u = 0; u < 8; ++u) {
        int col = u * 16 + m;
        unsigned* o = (unsigned*)(St + (size_t)col * NCH + r0 + quad * 4);
        o[0] = pk2(acc[u][0], acc[u][1]);
        o[1] = pk2(acc[u][2], acc[u][3]);
    }
}

// ---------------------------------------------------------------------------
// Fused edge pass + segment_sum + col-max.  Per wave: 8 consecutive nodes.
// Per node: tiles of 16 sorted edges; D = [x[dst], ef] @ We[128:264] via MFMA
// (5 ktiles); per valid row relu(D + S[n] + be) accumulated fp32; cross-quad
// shuffle reduce; plain bf16 store of the node row. ZERO global atomics.
// ---------------------------------------------------------------------------
__global__ __launch_bounds__(256) void k_edge2(
    const __bf16* __restrict__ xCur,
    const int*    __restrict__ offs,
    const int*    __restrict__ dsts,
    const __bf16* __restrict__ efs,
    const __bf16* __restrict__ St,
    const float*  __restrict__ We,    // 264x128 slice; rows 128..263 used
    const float*  __restrict__ be,
    __bf16* __restrict__ xNext,
    unsigned int* __restrict__ pmax, int stage)
{
    __shared__ __bf16 Wl[5 * 8 * 64 * 8];   // 40 KB
    __shared__ float  bl[HID];
    __shared__ unsigned int cm[HID];
    const int t = threadIdx.x;

    for (int idx = t; idx < 8 * 64 * 8; idx += 256) Wl[4 * 8 * 64 * 8 + idx] = (__bf16)0.f;
    if (t < HID) cm[t] = 0u;
    __syncthreads();
    for (int idx = t; idx < 128 * HID; idx += 256) {
        int k = idx >> 7, h = idx & 127;
        int kt = k >> 5, kk = k & 31;
        int lane = ((kk >> 3) << 4) | (h & 15);
        Wl[((((kt * 8) + (h >> 4)) * 64 + lane) << 3) | (kk & 7)] = f2bf(We[(size_t)(128 + k) * HID + h]);
    }
    for (int idx = t; idx < 8 * HID; idx += 256) {
        int k2 = idx >> 7, h = idx & 127;
        Wl[((((4 * 8) + (h >> 4)) * 64 + (h & 15)) << 3) | k2] = f2bf(We[(size_t)(256 + k2) * HID + h]);
    }
    for (int idx = t; idx < HID; idx += 256) bl[idx] = be[idx];
    __syncthreads();

    const int wave = t >> 6, lane = t & 63;
    const int m = lane & 15, quad = lane >> 4;
    const int gw = blockIdx.x * 4 + wave;    // grid 2048 -> 8192 waves
    const int n0 = gw * 8;                   // 8 nodes per wave, consecutive

    float mxu[8];
    #pragma unroll
    for (int u = 0; u < 8; ++u) mxu[u] = 0.f;

    for (int n = n0; n < n0 + 8; ++n) {
        const int j0 = offs[n], j1 = offs[n + 1];
        float tot[8];
        if (j0 == j1) {
            #pragma unroll
            for (int u = 0; u < 8; ++u) tot[u] = 0.f;
        } else {
            float Sb[8];
            #pragma unroll
            for (int u = 0; u < 8; ++u) {
                int col = u * 16 + m;
                Sb[u] = (float)St[(size_t)col * NCH + n] + bl[col];
            }
            float part[8];
            #pragma unroll
            for (int u = 0; u < 8; ++u) part[u] = 0.f;

            for (int j = j0; j < j1; j += 16) {
                int jc = j + m; if (jc > j1 - 1) jc = j1 - 1;
                const int dm = dsts[jc];
                const __bf16* rd = xCur + (size_t)dm * HID + quad * 8;
                bfrag a[5];
                #pragma unroll
                for (int kt = 0; kt < 4; ++kt) a[kt] = *(const bfrag*)(rd + kt * 32);
                {
                    bfrag z;
                    #pragma unroll
                    for (int q = 0; q < 8; ++q) z[q] = (__bf16)0.f;
                    if (quad == 0) z = *(const bfrag*)(efs + (size_t)jc * 8);
                    a[4] = z;
                }
                ffrag acc[8];
                #pragma unroll
                for (int u = 0; u < 8; ++u)
                    #pragma unroll
                    for (int r = 0; r < 4; ++r) acc[u][r] = 0.f;
                #pragma unroll
                for (int kt = 0; kt < 5; ++kt)
                    #pragma unroll
                    for (int u = 0; u < 8; ++u) {
                        bfrag b = *(const bfrag*)(&Wl[(((kt * 8 + u) * 64 + lane) << 3)]);
                        acc[u] = __builtin_amdgcn_mfma_f32_16x16x32_bf16(a[kt], b, acc[u], 0, 0, 0);
                    }
                const int rbase = j + quad * 4;
                #pragma unroll
                for (int r = 0; r < 4; ++r) {
                    if (rbase + r < j1) {
                        #pragma unroll
                        for (int u = 0; u < 8; ++u)
                            part[u] += fmaxf(acc[u][r] + Sb[u], 0.f);
                    }
                }
            }
            #pragma unroll
            for (int u = 0; u < 8; ++u) {
                float v = part[u];
                v += __shfl_xor(v, 16);
                v += __shfl_xor(v, 32);
                tot[u] = v;
            }
        }
        const int u0 = quad * 2;
        xNext[(size_t)n * HID + u0 * 16 + m]       = f2bf(tot[u0]);
        xNext[(size_t)n * HID + (u0 + 1) * 16 + m] = f2bf(tot[u0 + 1]);
        #pragma unroll
        for (int u = 0; u < 8; ++u) mxu[u] = fmaxf(mxu[u], tot[u]);
    }

    #pragma unroll
    for (int u = 0; u < 8; ++u) {
        float v = mxu[u];
        v = fmaxf(v, __shfl_xor(v, 16));
        v = fmaxf(v, __shfl_xor(v, 32));
        if (quad == 0) atomicMax(&cm[u * 16 + m], __float_as_uint(v));
    }
    __syncthreads();
    if (t < HID) atomicMax(&pmax[stage * HID + t], cm[t]);
}

// ---------------------------------------------------------------------------
// Fallback path kernels (R1-proven, 48 MB footprint)
// ---------------------------------------------------------------------------
__global__ __launch_bounds__(256) void k_edge_at(
    const __bf16* __restrict__ xA, const int* __restrict__ eidx,
    const float* __restrict__ ef, const float* __restrict__ We,
    const float* __restrict__ be, float* __restrict__ xNew)
{
    __shared__ __bf16 Wl[9 * 8 * 64 * 8];
    __shared__ float  bl[HID];
    const int t = threadIdx.x;
    for (int idx = t; idx < 8 * 64 * 8; idx += 256) Wl[8 * 8 * 64 * 8 + idx] = (__bf16)0.f;
    __syncthreads();
    for (int idx = t; idx < 256 * HID; idx += 256) {
        int k = idx >> 7, h = idx & 127;
        int kt = k >> 5, kk = k & 31;
        int lane = ((kk >> 3) << 4) | (h & 15);
        Wl[((((kt * 8) + (h >> 4)) * 64 + lane) << 3) | (kk & 7)] = f2bf(We[idx]);
    }
    for (int idx = t; idx < 8 * HID; idx += 256) {
        int k2 = idx >> 7, h = idx & 127;
        Wl[((((8 * 8) + (h >> 4)) * 64 + (h & 15)) << 3) | k2] = f2bf(We[(256 + k2) * HID + h]);
    }
    for (int idx = t; idx < HID; idx += 256) bl[idx] = be[idx];
    __syncthreads();

    const int wave = t >> 6, lane = t & 63;
    const int m = lane & 15, quad = lane >> 4;
    for (int c = 0; c < 8; ++c) {
        const int e0 = blockIdx.x * 512 + c * 64 + wave * 16;
        const int e  = e0 + m;
        const int src = eidx[2 * e], dst = eidx[2 * e + 1];
        const __bf16* rs = xA + (size_t)src * HID;
        const __bf16* rd = xA + (size_t)dst * HID;
        bfrag a[9];
        #pragma unroll
        for (int kt = 0; kt < 4; ++kt) a[kt] = *(const bfrag*)(rs + kt * 32 + quad * 8);
        #pragma unroll
        for (int kt = 4; kt < 8; ++kt) a[kt] = *(const bfrag*)(rd + (kt - 4) * 32 + quad * 8);
        {
            bfrag z;
            #pragma unroll
            for (int q = 0; q < 8; ++q) z[q] = (__bf16)0.f;
            if (quad == 0) {
                const float4* p = (const float4*)(ef + (size_t)e * 8);
                float4 f0 = p[0], f1 = p[1];
                z[0]=f2bf(f0.x); z[1]=f2bf(f0.y); z[2]=f2bf(f0.z); z[3]=f2bf(f0.w);
                z[4]=f2bf(f1.x); z[5]=f2bf(f1.y); z[6]=f2bf(f1.z); z[7]=f2bf(f1.w);
            }
            a[8] = z;
        }
        ffrag acc[8];
        #pragma unroll
        for (int u = 0; u < 8; ++u)
            #pragma unroll
            for (int r = 0; r < 4; ++r) acc[u][r] = 0.f;
        #pragma unroll
        for (int kt = 0; kt < 9; ++kt)
            #pragma unroll
            for (int u = 0; u < 8; ++u) {
                bfrag b = *(const bfrag*)(&Wl[(((kt * 8 + u) * 64 + lane) << 3)]);
                acc[u] = __builtin_amdgcn_mfma_f32_16x16x32_bf16(a[kt], b, acc[u], 0, 0, 0);
            }
        #pragma unroll
        for (int r = 0; r < 4; ++r) {
            int er = e0 + quad * 4 + r;
            int sr = eidx[2 * er];
            float* outrow = xNew + (size_t)sr * HID;
            #pragma unroll
            for (int u = 0; u < 8; ++u) {
                int col = u * 16 + m;
                atomicAdd(outrow + col, fmaxf(acc[u][r] + bl[col], 0.f));
            }
        }
    }
}

__global__ __launch_bounds__(256) void k_fin(
    float* __restrict__ xNew, __bf16* __restrict__ xA,
    unsigned int* __restrict__ pmax, int stage, int flags)
{
    const int t = threadIdx.x;
    const size_t total  = (size_t)NCH * HID;
    const size_t stride = (size_t)gridDim.x * 256;
    float mx = 0.f;
    for (size_t i = (size_t)blockIdx.x * 256 + t; i < total; i += stride) {
        float v = xNew[i];
        mx = fmaxf(mx, v);
        if (flags & 1) xA[i] = f2bf(v);
        if (flags & 2) xNew[i] = 0.f;
    }
    __shared__ float red[256];
    red[t] = mx;
    __syncthreads();
    if (t < 128) {
        float v = fmaxf(red[t], red[t + 128]);
        atomicMax(&pmax[stage * HID + t], __float_as_uint(v));
    }
}

// ---------------------------------------------------------------------------
// Parent head: out = relu(pmax(384) @ Wp + bp)
// ---------------------------------------------------------------------------
__global__ __launch_bounds__(128) void k_parent(
    const unsigned int* __restrict__ pmaxU,
    const float* __restrict__ Wp, const float* __restrict__ bp,
    float* __restrict__ out)
{
    __shared__ float pl[384];
    const int t = threadIdx.x;
    for (int i = t; i < 384; i += 128) pl[i] = __uint_as_float(pmaxU[i]);
    __syncthreads();
    float acc = bp[t];
    for (int j = 0; j < 384; ++j) acc += pl[j] * Wp[j * HID + t];
    out[t] = fmaxf(acc, 0.f);
}

extern "C" void kernel_launch(void* const* d_in, const int* in_sizes, int n_in,
                              void* d_out, int out_size, void* d_ws, size_t ws_size,
                              hipStream_t stream)
{
    const float* cf   = (const float*)d_in[0];
    const float* ex   = (const float*)d_in[1];
    const float* ef   = (const float*)d_in[2];
    const int*   eidx = (const int*)d_in[3];
    const float* Wc   = (const float*)d_in[4];
    const float* bc   = (const float*)d_in[5];
    const float* We   = (const float*)d_in[6];
    const float* be   = (const float*)d_in[7];
    const float* Wp   = (const float*)d_in[8];
    const float* bp   = (const float*)d_in[9];
    float* out = (float*)d_out;

    char* ws = (char*)d_ws;

    // CSR-fused path layout (~69 MB)
    const size_t OFF_XA   = 0;
    const size_t OFF_XB   = OFF_XA   + (size_t)NCH * HID * 2;   // +16 MB
    const size_t OFF_ST   = OFF_XB   + (size_t)NCH * HID * 2;   // +16 MB
    const size_t OFF_EFS  = OFF_ST   + (size_t)NCH * HID * 2;   // +16 MB
    const size_t OFF_PERM = OFF_EFS  + (size_t)NE * 8 * 2;      // +16 MB
    const size_t OFF_OFFS = OFF_PERM + (size_t)NE * 4;          // +4 MB
    const size_t OFF_DEG  = OFF_OFFS + 262400;
    const size_t OFF_CUR  = OFF_DEG  + 262144;
    const size_t OFF_PMAX = OFF_CUR  + 262144;
    const size_t NEED     = OFF_PMAX + 2048;

    if (ws_size >= NEED) {
        __bf16*       xA   = (__bf16*)(ws + OFF_XA);
        __bf16*       xB   = (__bf16*)(ws + OFF_XB);
        __bf16*       St   = (__bf16*)(ws + OFF_ST);
        __bf16*       efs  = (__bf16*)(ws + OFF_EFS);
        int*          perm = (int*)   (ws + OFF_PERM);
        int*          dsts = perm;                     // alias: safe (see k_sortef)
        int*          offs = (int*)   (ws + OFF_OFFS);
        int*          deg  = (int*)   (ws + OFF_DEG);
        int*          cur  = (int*)   (ws + OFF_CUR);
        unsigned int* pmax = (unsigned int*)(ws + OFF_PMAX);

        hipMemsetAsync(pmax, 0, 384 * sizeof(unsigned int), stream);
        hipMemsetAsync(deg, 0, NCH * sizeof(int), stream);

        k_child  <<<1024, 256, 0, stream>>>(cf, ex, Wc, bc, xA, pmax);
        k_hist   <<<4096, 256, 0, stream>>>(eidx, deg);
        k_scan   <<<1,   1024, 0, stream>>>(deg, offs, cur);
        k_scatter<<<4096, 256, 0, stream>>>(eidx, cur, perm);
        k_sortef <<<4096, 256, 0, stream>>>(eidx, perm, ef, dsts, efs);

        k_src    <<<1024, 256, 0, stream>>>(xA, We, St);
        k_edge2  <<<2048, 256, 0, stream>>>(xA, offs, dsts, efs, St, We, be, xB, pmax, 1);
        k_src    <<<1024, 256, 0, stream>>>(xB, We + 264 * HID, St);
        k_edge2  <<<2048, 256, 0, stream>>>(xB, offs, dsts, efs, St, We + 264 * HID, be + HID, xA, pmax, 2);
        k_parent <<<1,    128, 0, stream>>>(pmax, Wp, bp, out);
    } else {
        // fallback: R1 atomic path (48 MB)
        float*        xNew = (float*)ws;
        __bf16*       xA   = (__bf16*)(ws + (size_t)NCH * HID * 4);
        unsigned int* pmax = (unsigned int*)(ws + (size_t)NCH * HID * 6);

        hipMemsetAsync(pmax, 0, 384 * sizeof(unsigned int), stream);
        hipMemsetAsync(xNew, 0, (size_t)NCH * HID * 4, stream);

        k_child  <<<1024, 256, 0, stream>>>(cf, ex, Wc, bc, xA, pmax);
        k_edge_at<<<2048, 256, 0, stream>>>(xA, eidx, ef, We,             be,       xNew);
        k_fin    <<<512,  256, 0, stream>>>(xNew, xA, pmax, 1, 3);
        k_edge_at<<<2048, 256, 0, stream>>>(xA, eidx, ef, We + 264 * HID, be + HID, xNew);
        k_fin    <<<512,  256, 0, stream>>>(xNew, xA, pmax, 2, 0);
        k_parent <<<1,    128, 0, stream>>>(pmax, Wp, bp, out);
    }
}

// Round 4
// 658.448 us; speedup vs baseline: 1.8980x; 1.3557x over previous
//
#include <hip/hip_runtime.h>
#include <hip/hip_bf16.h>

#define HID 128
#define DIN 192      // N_FEAT + NUM_SEM
#define NCH 65536
#define NE  1048576

typedef __bf16 bfrag __attribute__((ext_vector_type(8)));
typedef float  ffrag __attribute__((ext_vector_type(4)));

static __device__ __forceinline__ __bf16 f2bf(float x) { return (__bf16)x; }
static __device__ __forceinline__ unsigned pk2(float a, float b) {
    __bf16 b0 = f2bf(a), b1 = f2bf(b);
    return (unsigned)*(unsigned short*)&b0 | ((unsigned)*(unsigned short*)&b1 << 16);
}

struct Frags { bfrag a[5]; };

// ---------------------------------------------------------------------------
// Child encoder fused: xA[n][h] = bf16(relu(cf[n]@Wc + bc) * exists[n]),
// col-max into pmax[0..127].
// ---------------------------------------------------------------------------
__global__ __launch_bounds__(256) void k_child(
    const float* __restrict__ cf, const float* __restrict__ exists,
    const float* __restrict__ Wc, const float* __restrict__ bc,
    __bf16* __restrict__ xA, unsigned int* __restrict__ pmax)
{
    __shared__ __bf16 Wl[6 * 8 * 64 * 8];   // 48 KB, B-fragment-swizzled
    __shared__ float  bl[HID];
    __shared__ unsigned int cm[HID];
    const int t = threadIdx.x;

    for (int idx = t; idx < DIN * HID; idx += 256) {
        int k = idx >> 7, h = idx & 127;
        int kt = k >> 5, kk = k & 31;
        int lane = ((kk >> 3) << 4) | (h & 15);
        Wl[((((kt * 8) + (h >> 4)) * 64 + lane) << 3) | (kk & 7)] = f2bf(Wc[idx]);
    }
    for (int idx = t; idx < HID; idx += 256) { bl[idx] = bc[idx]; cm[idx] = 0u; }
    __syncthreads();

    const int wave = t >> 6, lane = t & 63;
    const int m = lane & 15, quad = lane >> 4;

    const int tile = blockIdx.x * 4 + wave;   // grid 1024 -> 4096 tiles
    const int r0 = tile << 4;
    const int row = r0 + m;

    ffrag acc[8];
    #pragma unroll
    for (int u = 0; u < 8; ++u)
        #pragma unroll
        for (int r = 0; r < 4; ++r) acc[u][r] = 0.f;

    const float* arow = cf + (size_t)row * DIN + quad * 8;
    #pragma unroll
    for (int kt = 0; kt < 6; ++kt) {
        float4 f0 = *(const float4*)(arow + kt * 32);
        float4 f1 = *(const float4*)(arow + kt * 32 + 4);
        bfrag a;
        a[0]=f2bf(f0.x); a[1]=f2bf(f0.y); a[2]=f2bf(f0.z); a[3]=f2bf(f0.w);
        a[4]=f2bf(f1.x); a[5]=f2bf(f1.y); a[6]=f2bf(f1.z); a[7]=f2bf(f1.w);
        #pragma unroll
        for (int u = 0; u < 8; ++u) {
            bfrag b = *(const bfrag*)(&Wl[(((kt * 8 + u) * 64 + lane) << 3)]);
            acc[u] = __builtin_amdgcn_mfma_f32_16x16x32_bf16(a, b, acc[u], 0, 0, 0);
        }
    }

    float mxu[8];
    #pragma unroll
    for (int u = 0; u < 8; ++u) mxu[u] = 0.f;

    #pragma unroll
    for (int r = 0; r < 4; ++r) {
        int er = r0 + quad * 4 + r;
        float exv = exists[er];
        __bf16* orow = xA + (size_t)er * HID;
        #pragma unroll
        for (int u = 0; u < 8; ++u) {
            int col = u * 16 + m;
            float v = fmaxf(acc[u][r] + bl[col], 0.f) * exv;
            orow[col] = f2bf(v);
            mxu[u] = fmaxf(mxu[u], v);
        }
    }
    #pragma unroll
    for (int u = 0; u < 8; ++u) {
        float v = mxu[u];
        v = fmaxf(v, __shfl_xor(v, 16));
        v = fmaxf(v, __shfl_xor(v, 32));
        if (quad == 0) atomicMax(&cm[u * 16 + m], __float_as_uint(v));
    }
    __syncthreads();
    if (t < HID) atomicMax(&pmax[t], cm[t]);
}

// ---------------------------------------------------------------------------
// CSR build
// ---------------------------------------------------------------------------
__global__ __launch_bounds__(256) void k_hist(
    const int* __restrict__ eidx, int* __restrict__ deg)
{
    int e = blockIdx.x * 256 + threadIdx.x;
    atomicAdd(&deg[eidx[2 * e]], 1);
}

__global__ __launch_bounds__(1024) void k_scan(
    const int* __restrict__ deg, int* __restrict__ off, int* __restrict__ cursor)
{
    __shared__ int sc[1024];
    const int t = threadIdx.x;
    const int base = t * 64;
    int s = 0;
    for (int i = 0; i < 64; ++i) s += deg[base + i];
    sc[t] = s;
    __syncthreads();
    for (int o = 1; o < 1024; o <<= 1) {
        int v = (t >= o) ? sc[t - o] : 0;
        __syncthreads();
        sc[t] += v;
        __syncthreads();
    }
    int run = sc[t] - s;
    for (int i = 0; i < 64; ++i) {
        int v = deg[base + i];
        off[base + i] = run;
        cursor[base + i] = run;
        run += v;
    }
    if (t == 1023) off[NCH] = run;
}

// Scatter fused with dst/ef gather: coalesced ef read, scattered 16B/4B writes.
__global__ __launch_bounds__(256) void k_scatter(
    const int* __restrict__ eidx, int* __restrict__ cursor,
    const float* __restrict__ ef,
    int* __restrict__ dsts, __bf16* __restrict__ efs)
{
    int e = blockIdx.x * 256 + threadIdx.x;
    int s = eidx[2 * e], d = eidx[2 * e + 1];
    const float4* p = (const float4*)(ef + (size_t)e * 8);
    float4 f0 = p[0], f1 = p[1];
    int pos = atomicAdd(&cursor[s], 1);
    dsts[pos] = d;
    uint4 pk;
    pk.x = pk2(f0.x, f0.y); pk.y = pk2(f0.z, f0.w);
    pk.z = pk2(f1.x, f1.y); pk.w = pk2(f1.z, f1.w);
    *(uint4*)(efs + (size_t)pos * 8) = pk;
}

// ---------------------------------------------------------------------------
// St2[n][m][u] = bf16( (x @ We[0:128])[n][u*16+m] + be[u*16+m] )
// Frag-ordered so k_edge2 reads one 16B chunk per lane per node.
// ---------------------------------------------------------------------------
__global__ __launch_bounds__(256) void k_src(
    const __bf16* __restrict__ xCur, const float* __restrict__ We,
    const float* __restrict__ be, __bf16* __restrict__ St2)
{
    __shared__ __bf16 Wl[4 * 8 * 64 * 8];   // 32 KB
    __shared__ float  bl[HID];
    const int t = threadIdx.x;
    for (int idx = t; idx < 128 * HID; idx += 256) {
        int k = idx >> 7, h = idx & 127;
        int kt = k >> 5, kk = k & 31;
        int lane = ((kk >> 3) << 4) | (h & 15);
        Wl[((((kt * 8) + (h >> 4)) * 64 + lane) << 3) | (kk & 7)] = f2bf(We[idx]);
    }
    for (int idx = t; idx < HID; idx += 256) bl[idx] = be[idx];
    __syncthreads();

    const int wave = t >> 6, lane = t & 63;
    const int m = lane & 15, quad = lane >> 4;
    const int tile = blockIdx.x * 4 + wave;   // grid 1024 -> 4096 tiles
    const int r0 = tile << 4;
    const int row = r0 + m;

    ffrag acc[8];
    #pragma unroll
    for (int u = 0; u < 8; ++u)
        #pragma unroll
        for (int r = 0; r < 4; ++r) acc[u][r] = 0.f;

    const __bf16* ar = xCur + (size_t)row * HID + quad * 8;
    #pragma unroll
    for (int kt = 0; kt < 4; ++kt) {
        bfrag a = *(const bfrag*)(ar + kt * 32);
        #pragma unroll
        for (int u = 0; u < 8; ++u) {
            bfrag b = *(const bfrag*)(&Wl[(((kt * 8 + u) * 64 + lane) << 3)]);
            acc[u] = __builtin_amdgcn_mfma_f32_16x16x32_bf16(a, b, acc[u], 0, 0, 0);
        }
    }
    #pragma unroll
    for (int r = 0; r < 4; ++r) {
        int node = r0 + quad * 4 + r;
        bfrag pk;
        #pragma unroll
        for (int u = 0; u < 8; ++u) pk[u] = f2bf(acc[u][r] + bl[u * 16 + m]);
        *(bfrag*)(St2 + ((size_t)node * 16 + m) * 8) = pk;   // 16B coalesced
    }
}

// ---------------------------------------------------------------------------
// Fused edge pass + segment_sum + col-max.  Wave owns 4 consecutive nodes =
// one contiguous sorted-edge range.  dsts preloaded into 2 regs (shfl-served),
// 1-tile-ahead frag prefetch across node boundaries, acc initialized with
// S[n]+bias.  Zero global atomics on the data path.
// ---------------------------------------------------------------------------
__global__ __launch_bounds__(256) void k_edge2(
    const __bf16* __restrict__ xCur,
    const int*    __restrict__ offs,
    const int*    __restrict__ dsts,
    const __bf16* __restrict__ efs,
    const __bf16* __restrict__ St2,
    const float*  __restrict__ We,    // 264x128 slice; rows 128..263 used
    __bf16* __restrict__ xNext,
    unsigned int* __restrict__ pmax, int stage)
{
    __shared__ __bf16 Wl[5 * 8 * 64 * 8];   // 40 KB
    __shared__ unsigned int cm[HID];
    const int t = threadIdx.x;

    for (int idx = t; idx < 8 * 64 * 8; idx += 256) Wl[4 * 8 * 64 * 8 + idx] = (__bf16)0.f;
    if (t < HID) cm[t] = 0u;
    __syncthreads();
    for (int idx = t; idx < 128 * HID; idx += 256) {
        int k = idx >> 7, h = idx & 127;
        int kt = k >> 5, kk = k & 31;
        int lane = ((kk >> 3) << 4) | (h & 15);
        Wl[((((kt * 8) + (h >> 4)) * 64 + lane) << 3) | (kk & 7)] = f2bf(We[(size_t)(128 + k) * HID + h]);
    }
    for (int idx = t; idx < 8 * HID; idx += 256) {
        int k2 = idx >> 7, h = idx & 127;
        Wl[((((4 * 8) + (h >> 4)) * 64 + (h & 15)) << 3) | k2] = f2bf(We[(size_t)(256 + k2) * HID + h]);
    }
    __syncthreads();

    const int wave = t >> 6, lane = t & 63;
    const int m = lane & 15, quad = lane >> 4;
    const int gw = blockIdx.x * 4 + wave;    // grid 4096 -> 16384 waves
    const int n0 = gw * 4;                   // 4 nodes per wave, consecutive

    const int o0 = offs[n0],     o1 = offs[n0 + 1], o2 = offs[n0 + 2];
    const int o3 = offs[n0 + 3], o4 = offs[n0 + 4];

    auto selo = [&](int q) -> int {
        return (q <= 0) ? o0 : (q == 1) ? o1 : (q == 2) ? o2 : (q == 3) ? o3 : o4;
    };

    float mxu[8];
    #pragma unroll
    for (int u = 0; u < 8; ++u) mxu[u] = 0.f;

    if (o0 < o4) {
        const int dvA = dsts[min(o0 + lane, o4 - 1)];
        const int dvB = dsts[min(o0 + 64 + lane, o4 - 1)];

        auto LOADT = [&](int j) -> Frags {
            Frags f;
            int jl = j + m; jl = (jl < o4) ? jl : (o4 - 1);
            int rel = jl - o0;
            int dA = __shfl(dvA, rel & 63);
            int dB = __shfl(dvB, rel & 63);
            int dm;
            if (rel < 64)       dm = dA;
            else if (rel < 128) dm = dB;
            else                dm = dsts[jl];      // ultra-rare fallback
            const __bf16* rd = xCur + (size_t)dm * HID + quad * 8;
            f.a[0] = *(const bfrag*)(rd);
            f.a[1] = *(const bfrag*)(rd + 32);
            f.a[2] = *(const bfrag*)(rd + 64);
            f.a[3] = *(const bfrag*)(rd + 96);
            bfrag z;
            #pragma unroll
            for (int q = 0; q < 8; ++q) z[q] = (__bf16)0.f;
            if (quad == 0) z = *(const bfrag*)(efs + (size_t)jl * 8);
            f.a[4] = z;
            return f;
        };

        int ci = 0;
        while (selo(ci) == selo(ci + 1)) ++ci;   // first non-empty node (exists)
        int cj = selo(ci);

        bfrag sb = *(const bfrag*)(St2 + ((size_t)(n0 + ci) * 16 + m) * 8);
        float part[8];
        #pragma unroll
        for (int u = 0; u < 8; ++u) part[u] = 0.f;

        Frags aC = LOADT(cj);

        for (;;) {
            const int cEnd = selo(ci + 1);
            int ni = ci, nj = cj + 16;
            if (nj >= cEnd) {
                ni = ci + 1;
                while (ni < 4 && selo(ni) == selo(ni + 1)) ++ni;
                nj = (ni < 4) ? selo(ni) : 0;
            }
            const bool hn = (ni < 4);
            Frags aN;
            if (hn) aN = LOADT(nj);             // prefetch next tile

            ffrag acc[8];
            #pragma unroll
            for (int u = 0; u < 8; ++u) {
                float s = (float)sb[u];
                acc[u][0] = s; acc[u][1] = s; acc[u][2] = s; acc[u][3] = s;
            }
            #pragma unroll
            for (int kt = 0; kt < 5; ++kt)
                #pragma unroll
                for (int u = 0; u < 8; ++u) {
                    bfrag b = *(const bfrag*)(&Wl[(((kt * 8 + u) * 64 + lane) << 3)]);
                    acc[u] = __builtin_amdgcn_mfma_f32_16x16x32_bf16(aC.a[kt], b, acc[u], 0, 0, 0);
                }

            const int rb = cj + quad * 4;
            #pragma unroll
            for (int r = 0; r < 4; ++r) {
                if (rb + r < cEnd) {
                    #pragma unroll
                    for (int u = 0; u < 8; ++u)
                        part[u] += fmaxf(acc[u][r], 0.f);
                }
            }

            if (!hn || ni != ci) {
                float tot[8];
                #pragma unroll
                for (int u = 0; u < 8; ++u) {
                    float v = part[u];
                    v += __shfl_xor(v, 16);
                    v += __shfl_xor(v, 32);
                    tot[u] = v;
                    mxu[u] = fmaxf(mxu[u], v);
                }
                // static-index selection of this quad's 2 columns (no scratch)
                float sA = (quad == 0) ? tot[0] : (quad == 1) ? tot[2] : (quad == 2) ? tot[4] : tot[6];
                float sB = (quad == 0) ? tot[1] : (quad == 1) ? tot[3] : (quad == 2) ? tot[5] : tot[7];
                const int n = n0 + ci, u0 = quad * 2;
                xNext[(size_t)n * HID + u0 * 16 + m]      = f2bf(sA);
                xNext[(size_t)n * HID + u0 * 16 + 16 + m] = f2bf(sB);
                if (hn) {
                    sb = *(const bfrag*)(St2 + ((size_t)(n0 + ni) * 16 + m) * 8);
                    #pragma unroll
                    for (int u = 0; u < 8; ++u) part[u] = 0.f;
                }
            }
            if (!hn) break;
            aC = aN; ci = ni; cj = nj;
        }
    }

    // zero rows for empty nodes
    {
        const int u0 = quad * 2;
        const __bf16 zz = (__bf16)0.f;
        if (o0 == o1) { xNext[(size_t)(n0+0)*HID + u0*16 + m] = zz; xNext[(size_t)(n0+0)*HID + u0*16 + 16 + m] = zz; }
        if (o1 == o2) { xNext[(size_t)(n0+1)*HID + u0*16 + m] = zz; xNext[(size_t)(n0+1)*HID + u0*16 + 16 + m] = zz; }
        if (o2 == o3) { xNext[(size_t)(n0+2)*HID + u0*16 + m] = zz; xNext[(size_t)(n0+2)*HID + u0*16 + 16 + m] = zz; }
        if (o3 == o4) { xNext[(size_t)(n0+3)*HID + u0*16 + m] = zz; xNext[(size_t)(n0+3)*HID + u0*16 + 16 + m] = zz; }
    }

    #pragma unroll
    for (int u = 0; u < 8; ++u) {
        float v = mxu[u];
        v = fmaxf(v, __shfl_xor(v, 16));
        v = fmaxf(v, __shfl_xor(v, 32));
        if (quad == 0) atomicMax(&cm[u * 16 + m], __float_as_uint(v));
    }
    __syncthreads();
    if (t < HID) atomicMax(&pmax[stage * HID + t], cm[t]);
}

// ---------------------------------------------------------------------------
// Fallback path kernels (R1-proven, 48 MB footprint)
// ---------------------------------------------------------------------------
__global__ __launch_bounds__(256) void k_edge_at(
    const __bf16* __restrict__ xA, const int* __restrict__ eidx,
    const float* __restrict__ ef, const float* __restrict__ We,
    const float* __restrict__ be, float* __restrict__ xNew)
{
    __shared__ __bf16 Wl[9 * 8 * 64 * 8];
    __shared__ float  bl[HID];
    const int t = threadIdx.x;
    for (int idx = t; idx < 8 * 64 * 8; idx += 256) Wl[8 * 8 * 64 * 8 + idx] = (__bf16)0.f;
    __syncthreads();
    for (int idx = t; idx < 256 * HID; idx += 256) {
        int k = idx >> 7, h = idx & 127;
        int kt = k >> 5, kk = k & 31;
        int lane = ((kk >> 3) << 4) | (h & 15);
        Wl[((((kt * 8) + (h >> 4)) * 64 + lane) << 3) | (kk & 7)] = f2bf(We[idx]);
    }
    for (int idx = t; idx < 8 * HID; idx += 256) {
        int k2 = idx >> 7, h = idx & 127;
        Wl[((((8 * 8) + (h >> 4)) * 64 + (h & 15)) << 3) | k2] = f2bf(We[(256 + k2) * HID + h]);
    }
    for (int idx = t; idx < HID; idx += 256) bl[idx] = be[idx];
    __syncthreads();

    const int wave = t >> 6, lane = t & 63;
    const int m = lane & 15, quad = lane >> 4;
    for (int c = 0; c < 8; ++c) {
        const int e0 = blockIdx.x * 512 + c * 64 + wave * 16;
        const int e  = e0 + m;
        const int src = eidx[2 * e], dst = eidx[2 * e + 1];
        const __bf16* rs = xA + (size_t)src * HID;
        const __bf16* rd = xA + (size_t)dst * HID;
        bfrag a[9];
        #pragma unroll
        for (int kt = 0; kt < 4; ++kt) a[kt] = *(const bfrag*)(rs + kt * 32 + quad * 8);
        #pragma unroll
        for (int kt = 4; kt < 8; ++kt) a[kt] = *(const bfrag*)(rd + (kt - 4) * 32 + quad * 8);
        {
            bfrag z;
            #pragma unroll
            for (int q = 0; q < 8; ++q) z[q] = (__bf16)0.f;
            if (quad == 0) {
                const float4* p = (const float4*)(ef + (size_t)e * 8);
                float4 f0 = p[0], f1 = p[1];
                z[0]=f2bf(f0.x); z[1]=f2bf(f0.y); z[2]=f2bf(f0.z); z[3]=f2bf(f0.w);
                z[4]=f2bf(f1.x); z[5]=f2bf(f1.y); z[6]=f2bf(f1.z); z[7]=f2bf(f1.w);
            }
            a[8] = z;
        }
        ffrag acc[8];
        #pragma unroll
        for (int u = 0; u < 8; ++u)
            #pragma unroll
            for (int r = 0; r < 4; ++r) acc[u][r] = 0.f;
        #pragma unroll
        for (int kt = 0; kt < 9; ++kt)
            #pragma unroll
            for (int u = 0; u < 8; ++u) {
                bfrag b = *(const bfrag*)(&Wl[(((kt * 8 + u) * 64 + lane) << 3)]);
                acc[u] = __builtin_amdgcn_mfma_f32_16x16x32_bf16(a[kt], b, acc[u], 0, 0, 0);
            }
        #pragma unroll
        for (int r = 0; r < 4; ++r) {
            int er = e0 + quad * 4 + r;
            int sr = eidx[2 * er];
            float* outrow = xNew + (size_t)sr * HID;
            #pragma unroll
            for (int u = 0; u < 8; ++u) {
                int col = u * 16 + m;
                atomicAdd(outrow + col, fmaxf(acc[u][r] + bl[col], 0.f));
            }
        }
    }
}

__global__ __launch_bounds__(256) void k_fin(
    float* __restrict__ xNew, __bf16* __restrict__ xA,
    unsigned int* __restrict__ pmax, int stage, int flags)
{
    const int t = threadIdx.x;
    const size_t total  = (size_t)NCH * HID;
    const size_t stride = (size_t)gridDim.x * 256;
    float mx = 0.f;
    for (size_t i = (size_t)blockIdx.x * 256 + t; i < total; i += stride) {
        float v = xNew[i];
        mx = fmaxf(mx, v);
        if (flags & 1) xA[i] = f2bf(v);
        if (flags & 2) xNew[i] = 0.f;
    }
    __shared__ float red[256];
    red[t] = mx;
    __syncthreads();
    if (t < 128) {
        float v = fmaxf(red[t], red[t + 128]);
        atomicMax(&pmax[stage * HID + t], __float_as_uint(v));
    }
}

// ---------------------------------------------------------------------------
// Parent head: out = relu(pmax(384) @ Wp + bp)
// ---------------------------------------------------------------------------
__global__ __launch_bounds__(128) void k_parent(
    const unsigned int* __restrict__ pmaxU,
    const float* __restrict__ Wp, const float* __restrict__ bp,
    float* __restrict__ out)
{
    __shared__ float pl[384];
    const int t = threadIdx.x;
    for (int i = t; i < 384; i += 128) pl[i] = __uint_as_float(pmaxU[i]);
    __syncthreads();
    float acc = bp[t];
    for (int j = 0; j < 384; ++j) acc += pl[j] * Wp[j * HID + t];
    out[t] = fmaxf(acc, 0.f);
}

extern "C" void kernel_launch(void* const* d_in, const int* in_sizes, int n_in,
                              void* d_out, int out_size, void* d_ws, size_t ws_size,
                              hipStream_t stream)
{
    const float* cf   = (const float*)d_in[0];
    const float* ex   = (const float*)d_in[1];
    const float* ef   = (const float*)d_in[2];
    const int*   eidx = (const int*)d_in[3];
    const float* Wc   = (const float*)d_in[4];
    const float* bc   = (const float*)d_in[5];
    const float* We   = (const float*)d_in[6];
    const float* be   = (const float*)d_in[7];
    const float* Wp   = (const float*)d_in[8];
    const float* bp   = (const float*)d_in[9];
    float* out = (float*)d_out;

    char* ws = (char*)d_ws;

    // CSR-fused path layout (~69 MB)
    const size_t OFF_XA   = 0;
    const size_t OFF_XB   = OFF_XA   + (size_t)NCH * HID * 2;   // +16 MB
    const size_t OFF_ST   = OFF_XB   + (size_t)NCH * HID * 2;   // +16 MB
    const size_t OFF_EFS  = OFF_ST   + (size_t)NCH * HID * 2;   // +16 MB
    const size_t OFF_DST  = OFF_EFS  + (size_t)NE * 8 * 2;      // +16 MB
    const size_t OFF_OFFS = OFF_DST  + (size_t)NE * 4;          // +4 MB
    const size_t OFF_DEG  = OFF_OFFS + 262400;
    const size_t OFF_CUR  = OFF_DEG  + 262144;
    const size_t OFF_PMAX = OFF_CUR  + 262144;
    const size_t NEED     = OFF_PMAX + 2048;

    if (ws_size >= NEED) {
        __bf16*       xA   = (__bf16*)(ws + OFF_XA);
        __bf16*       xB   = (__bf16*)(ws + OFF_XB);
        __bf16*       St2  = (__bf16*)(ws + OFF_ST);
        __bf16*       efs  = (__bf16*)(ws + OFF_EFS);
        int*          dsts = (int*)   (ws + OFF_DST);
        int*          offs = (int*)   (ws + OFF_OFFS);
        int*          deg  = (int*)   (ws + OFF_DEG);
        int*          cur  = (int*)   (ws + OFF_CUR);
        unsigned int* pmax = (unsigned int*)(ws + OFF_PMAX);

        hipMemsetAsync(pmax, 0, 384 * sizeof(unsigned int), stream);
        hipMemsetAsync(deg, 0, NCH * sizeof(int), stream);

        k_child  <<<1024, 256, 0, stream>>>(cf, ex, Wc, bc, xA, pmax);
        k_hist   <<<4096, 256, 0, stream>>>(eidx, deg);
        k_scan   <<<1,   1024, 0, stream>>>(deg, offs, cur);
        k_scatter<<<4096, 256, 0, stream>>>(eidx, cur, ef, dsts, efs);

        k_src    <<<1024, 256, 0, stream>>>(xA, We, be, St2);
        k_edge2  <<<4096, 256, 0, stream>>>(xA, offs, dsts, efs, St2, We, xB, pmax, 1);
        k_src    <<<1024, 256, 0, stream>>>(xB, We + 264 * HID, be + HID, St2);
        k_edge2  <<<4096, 256, 0, stream>>>(xB, offs, dsts, efs, St2, We + 264 * HID, xA, pmax, 2);
        k_parent <<<1,    128, 0, stream>>>(pmax, Wp, bp, out);
    } else {
        // fallback: R1 atomic path (48 MB)
        float*        xNew = (float*)ws;
        __bf16*       xA   = (__bf16*)(ws + (size_t)NCH * HID * 4);
        unsigned int* pmax = (unsigned int*)(ws + (size_t)NCH * HID * 6);

        hipMemsetAsync(pmax, 0, 384 * sizeof(unsigned int), stream);
        hipMemsetAsync(xNew, 0, (size_t)NCH * HID * 4, stream);

        k_child  <<<1024, 256, 0, stream>>>(cf, ex, Wc, bc, xA, pmax);
        k_edge_at<<<2048, 256, 0, stream>>>(xA, eidx, ef, We,             be,       xNew);
        k_fin    <<<512,  256, 0, stream>>>(xNew, xA, pmax, 1, 3);
        k_edge_at<<<2048, 256, 0, stream>>>(xA, eidx, ef, We + 264 * HID, be + HID, xNew);
        k_fin    <<<512,  256, 0, stream>>>(xNew, xA, pmax, 2, 0);
        k_parent <<<1,    128, 0, stream>>>(pmax, Wp, bp, out);
    }
}